// Round 16
// baseline (76.257 us; speedup 1.0000x reference)
//
#include <hip/hip_runtime.h>
#include <hip/hip_bf16.h>

// ---------------------------------------------------------------------------
// BlockedMLP: out = (relu(bsr(relu(x@W1^T+b1))+b2)) @ W3^T + b3
// B=2048, IN=1024, H=2048, OUT=1024, BS=32, RB=CB=64, 32 blocks/row
// Round 16: R15 base (best, 75.9us). Single delta: L3 -> PIPE=3 at 64x32
// (36KB LDS, still 4 blocks/CU: floor(160/36)=4). Isolates "deeper
// prefetch at CONSTANT occupancy" — the one geometry cell where pipeline
// depth doesn't trade against blocks/CU. L3 has 32 K-steps (most
// latency-exposed kernel).
// ---------------------------------------------------------------------------

typedef __attribute__((ext_vector_type(8))) short bf16x8;
typedef __attribute__((ext_vector_type(4))) float f32x4;

__device__ __forceinline__ unsigned short f2bf(float f) {
    union { float f; unsigned int u; } c; c.f = f;
    unsigned int u = c.u;
    u += 0x7fffu + ((u >> 16) & 1u);   // round-to-nearest-even
    return (unsigned short)(u >> 16);
}

__device__ __forceinline__ void async16(const void* g, void* l) {
    __builtin_amdgcn_global_load_lds(
        (const __attribute__((address_space(1))) void*)g,
        (__attribute__((address_space(3))) void*)l,
        16, 0, 0);
}

template<int N>
__device__ __forceinline__ void vm_wait() {
    asm volatile("s_waitcnt vmcnt(%0)" :: "n"(N) : "memory");
}
__device__ __forceinline__ void barrier() {
    asm volatile("" ::: "memory");
    __builtin_amdgcn_s_barrier();
    asm volatile("" ::: "memory");
}

// ---------------------------------------------------------------------------
// cvt2: f32 -> bf16 for x and W1 only (2 x 2^21 elems), grid 4096
// ---------------------------------------------------------------------------
__global__ __launch_bounds__(256) void cvt2(
    const float* __restrict__ x, const float* __restrict__ w1,
    unsigned short* __restrict__ xb, unsigned short* __restrict__ w1b)
{
    const int NE = 1 << 21;
    int e = (blockIdx.x * 256 + threadIdx.x) * 4;
    int a = e >> 21;
    int off = e & (NE - 1);
    const float* src = a ? w1 : x;
    unsigned short* dst = a ? w1b : xb;
    float4 vv = *reinterpret_cast<const float4*>(src + off);
    ushort4 o;
    o.x = f2bf(vv.x); o.y = f2bf(vv.y); o.z = f2bf(vv.z); o.w = f2bf(vv.w);
    *reinterpret_cast<ushort4*>(dst + off) = o;
}

// ---------------------------------------------------------------------------
// bf16 GEMM, B^T form: BM x BN tile, BK=64, 4 waves (2x2), PIPE-deep LDS
// dbuf, two-barrier counted-vmcnt, XOR swizzle chunk^(row&7), XCD-pinned.
// PRECVT: convert 2048 elems each of two f32 arrays per block (producers
// for LATER kernels; hidden under pipeline fill).
// OUTMODE: 0 = f32+bias, 1 = bf16+bias.
// ---------------------------------------------------------------------------
template<int BM, int BN, int MCL, int PIPE, int RELU, int OUTMODE, int PRECVT>
__global__ __launch_bounds__(256) void gemm_bt(
    const unsigned short* __restrict__ A,
    const unsigned short* __restrict__ B,
    const float* __restrict__ bias,
    void* __restrict__ C0,
    int M, int N, int K,
    const float* __restrict__ cs0, unsigned short* __restrict__ cd0,
    const float* __restrict__ cs1, unsigned short* __restrict__ cd1)
{
    constexpr int BK = 64;
    constexpr int MR = BM / 32;
    constexpr int NR = BN / 32;
    constexpr int AI = BM / 32;
    constexpr int BI = BN / 32;
    constexpr int LPS = AI + BI;
    __shared__ unsigned short As[PIPE][BM * BK];
    __shared__ unsigned short Bs[PIPE][BN * BK];

    const int t = threadIdx.x;
    const int w = t >> 6;
    const int l = t & 63;
    const int id = blockIdx.x;

    const int xcd = id & 7;
    const int j = id >> 3;
    const int mt = xcd * MCL + (j & (MCL - 1));
    const int nt = j / MCL;
    const int bm = mt * BM;
    const int bn = nt * BN;

    const int wm = (w >> 1) * (BM / 2);
    const int wn = (w & 1) * (BN / 2);

    f32x4 acc[MR][NR];
    #pragma unroll
    for (int i = 0; i < MR; ++i)
        #pragma unroll
        for (int jj = 0; jj < NR; ++jj)
            acc[i][jj] = (f32x4){0.f, 0.f, 0.f, 0.f};

    const int arow = bm + w * (BM / 4) + (l >> 3);
    const int brow = bn + w * (BN / 4) + (l >> 3);
    const int scol = ((l & 7) ^ (l >> 3)) * 8;
    const int fr = l & 15;
    const int kg = l >> 4;
    const int fq = l >> 4;

    auto stage = [&](int buf, int kt) {
        const int k0 = kt * BK;
        #pragma unroll
        for (int i = 0; i < AI; ++i)
            async16(A + (size_t)(arow + i * 8) * K + k0 + scol,
                    &As[buf][(w * (BM / 4) + i * 8) * BK]);
        #pragma unroll
        for (int i = 0; i < BI; ++i)
            async16(B + (size_t)(brow + i * 8) * K + k0 + scol,
                    &Bs[buf][(w * (BN / 4) + i * 8) * BK]);
    };

    auto compute = [&](int buf) {
        #pragma unroll
        for (int kk = 0; kk < 2; ++kk) {
            const int pc = ((kk * 4 + kg) ^ (fr & 7)) * 8;
            bf16x8 af[MR], bg[NR];
            #pragma unroll
            for (int i = 0; i < MR; ++i)
                af[i] = *reinterpret_cast<const bf16x8*>(
                    &As[buf][(wm + i * 16 + fr) * BK + pc]);
            #pragma unroll
            for (int jj = 0; jj < NR; ++jj)
                bg[jj] = *reinterpret_cast<const bf16x8*>(
                    &Bs[buf][(wn + jj * 16 + fr) * BK + pc]);
            #pragma unroll
            for (int i = 0; i < MR; ++i)
                #pragma unroll
                for (int jj = 0; jj < NR; ++jj)
                    acc[i][jj] = __builtin_amdgcn_mfma_f32_16x16x32_bf16(
                        af[i], bg[jj], acc[i][jj], 0, 0, 0);
        }
    };

    const int nK = K >> 6;
    stage(0, 0);
    stage(1, 1);
    if (PIPE == 3) stage(2, 2);

    if (PRECVT) {
        // converts run while the first staged tiles are in flight; these
        // f32 loads are NEWER than the staged tiles in the vmcnt queue, so
        // counted waits on older staging loads remain conservative-safe.
        const int off = id * 2048 + t * 8;
        float4 a0 = *reinterpret_cast<const float4*>(cs0 + off);
        float4 a1 = *reinterpret_cast<const float4*>(cs0 + off + 4);
        float4 b0 = *reinterpret_cast<const float4*>(cs1 + off);
        float4 b1 = *reinterpret_cast<const float4*>(cs1 + off + 4);
        ushort4 o0, o1, o2, o3;
        o0.x = f2bf(a0.x); o0.y = f2bf(a0.y); o0.z = f2bf(a0.z); o0.w = f2bf(a0.w);
        o1.x = f2bf(a1.x); o1.y = f2bf(a1.y); o1.z = f2bf(a1.z); o1.w = f2bf(a1.w);
        o2.x = f2bf(b0.x); o2.y = f2bf(b0.y); o2.z = f2bf(b0.z); o2.w = f2bf(b0.w);
        o3.x = f2bf(b1.x); o3.y = f2bf(b1.y); o3.z = f2bf(b1.z); o3.w = f2bf(b1.w);
        *reinterpret_cast<ushort4*>(cd0 + off)     = o0;
        *reinterpret_cast<ushort4*>(cd0 + off + 4) = o1;
        *reinterpret_cast<ushort4*>(cd1 + off)     = o2;
        *reinterpret_cast<ushort4*>(cd1 + off + 4) = o3;
    }

    int cur = 0;
    for (int kt = 0; kt < nK; ++kt) {
        if (PIPE == 3) {
            if (kt < nK - 2)       vm_wait<2 * LPS>();
            else if (kt == nK - 2) vm_wait<LPS>();
            else                   vm_wait<0>();
        } else {
            if (kt < nK - 1)       vm_wait<LPS>();
            else                   vm_wait<0>();
        }
        barrier();
        compute(cur);
        if (kt + PIPE < nK) {
            barrier();
            stage(cur, kt + PIPE);
        } else if (kt + 1 < nK) {
            barrier();
        }
        cur = (cur == PIPE - 1) ? 0 : cur + 1;
    }

    // epilogue: C/D layout col = l&15, row = (l>>4)*4 + v
    #pragma unroll
    for (int i = 0; i < MR; ++i) {
        const int row0 = bm + wm + i * 16 + fq * 4;
        #pragma unroll
        for (int jj = 0; jj < NR; ++jj) {
            const int col = bn + wn + jj * 16 + fr;
            const float bv = bias[col];
            #pragma unroll
            for (int v = 0; v < 4; ++v) {
                float r = acc[i][jj][v] + bv;
                if (RELU) r = fmaxf(r, 0.f);
                const size_t off = (size_t)(row0 + v) * N + col;
                if (OUTMODE == 1) ((unsigned short*)C0)[off] = f2bf(r);
                else              ((float*)C0)[off] = r;
            }
        }
    }
}

// ---------------------------------------------------------------------------
// BSR layer (R8-exact): 2 nnz blocks per K-step, counted-vmcnt, grid 1024
// (4 blocks/CU), XCD-pinned, 128B LDS rows XOR-swizzled.
// ---------------------------------------------------------------------------
__global__ __launch_bounds__(256) void bsr_layer(
    const unsigned short* __restrict__ h,
    const int* __restrict__ crow,
    const int* __restrict__ cols,
    const unsigned short* __restrict__ vals,
    const float* __restrict__ b2,
    unsigned short* __restrict__ h2)
{
    __shared__ unsigned short Hs[2][128 * 64];
    __shared__ unsigned short Vs[2][32 * 64];
    __shared__ int colsS[64];
    const int t = threadIdx.x;
    const int w = t >> 6;
    const int l = t & 63;

    const int id = blockIdx.x;
    const int xcd = id & 7;
    const int j2 = id >> 3;
    const int bt = xcd * 2 + (j2 & 1);
    const int r  = j2 >> 1;
    const int bm = bt * 128;

    const int s = crow[r];
    const int cnt = crow[r + 1] - s;
    const int wrow = w * 32;

    if (t < cnt) colsS[t] = cols[s + t];

    f32x4 acc[2][2];
    #pragma unroll
    for (int i = 0; i < 2; ++i)
        #pragma unroll
        for (int jj = 0; jj < 2; ++jj)
            acc[i][jj] = (f32x4){0.f, 0.f, 0.f, 0.f};

    const int fr = l & 15;
    const int kg = l >> 4;
    const int lr = l >> 3;
    const int sc = (l & 7) ^ lr;

    auto stage = [&](int buf, int js) {
        const int n0 = s + 2 * js;
        const bool tail = (2 * js + 1 >= cnt);
        const int c0 = colsS[2 * js];
        const int c1 = tail ? c0 : colsS[2 * js + 1];
        const int n1 = tail ? n0 : n0 + 1;
        #pragma unroll
        for (int i = 0; i < 4; ++i) {
            const int row = bm + w * 32 + i * 8 + lr;
            const int col = (sc & 4) ? c1 * 32 + (sc & 3) * 8 : c0 * 32 + sc * 8;
            async16(h + (size_t)row * 2048 + col,
                    &Hs[buf][(w * 32 + i * 8) * 64]);
        }
        const int vrow = w * 8 + lr;
        if (!tail || !(sc & 4)) {
            const unsigned short* src =
                vals + (size_t)((sc & 4) ? n1 : n0) * 1024 + vrow * 32 + (sc & 3) * 8;
            async16(src, &Vs[buf][(w * 8) * 64]);
        } else {
            bf16x8 z = (bf16x8){0,0,0,0,0,0,0,0};
            *reinterpret_cast<bf16x8*>(&Vs[buf][vrow * 64 + (l & 7) * 8]) = z;
        }
    };

    auto compute = [&](int buf) {
        #pragma unroll
        for (int kk = 0; kk < 2; ++kk) {
            const int pc = ((kk * 4 + kg) ^ (fr & 7)) * 8;
            bf16x8 af[2], bg[2];
            #pragma unroll
            for (int i = 0; i < 2; ++i)
                af[i] = *reinterpret_cast<const bf16x8*>(
                    &Hs[buf][(wrow + i * 16 + fr) * 64 + pc]);
            #pragma unroll
            for (int jj = 0; jj < 2; ++jj)
                bg[jj] = *reinterpret_cast<const bf16x8*>(
                    &Vs[buf][(jj * 16 + fr) * 64 + pc]);
            #pragma unroll
            for (int i = 0; i < 2; ++i)
                #pragma unroll
                for (int jj = 0; jj < 2; ++jj)
                    acc[i][jj] = __builtin_amdgcn_mfma_f32_16x16x32_bf16(
                        af[i], bg[jj], acc[i][jj], 0, 0, 0);
        }
    };

    __syncthreads();
    const int nsteps = (cnt + 1) >> 1;
    stage(0, 0);
    if (nsteps > 1) stage(1, 1);
    int cur = 0;
    for (int js = 0; js < nsteps - 1; ++js) {
        vm_wait<5>();
        barrier();
        compute(cur);
        barrier();
        if (js + 2 < nsteps) stage(cur, js + 2);
        cur ^= 1;
    }
    vm_wait<0>();
    barrier();
    compute(cur);

    const int fq = l >> 4;
    #pragma unroll
    for (int i = 0; i < 2; ++i) {
        const int row0 = bm + wrow + i * 16 + fq * 4;
        #pragma unroll
        for (int jj = 0; jj < 2; ++jj) {
            const int col = r * 32 + jj * 16 + fr;
            const float bv = b2[col];
            #pragma unroll
            for (int v = 0; v < 4; ++v) {
                float rv = fmaxf(acc[i][jj][v] + bv, 0.f);
                h2[(size_t)(row0 + v) * 2048 + col] = f2bf(rv);
            }
        }
    }
}

// ---------------------------------------------------------------------------
extern "C" void kernel_launch(void* const* d_in, const int* in_sizes, int n_in,
                              void* d_out, int out_size, void* d_ws, size_t ws_size,
                              hipStream_t stream) {
    const float* x    = (const float*)d_in[0];   // 2048x1024
    const float* W1   = (const float*)d_in[1];   // 2048x1024
    const float* b1   = (const float*)d_in[2];   // 2048
    const int*   crow = (const int*)d_in[3];     // 65
    const int*   cols = (const int*)d_in[4];     // 2048
    const float* vals = (const float*)d_in[5];   // 2048x32x32
    const float* b2   = (const float*)d_in[6];   // 2048
    const float* W3   = (const float*)d_in[7];   // 1024x2048
    const float* b3   = (const float*)d_in[8];   // 1024
    float* out = (float*)d_out;                  // 2048x1024 f32

    const int NE = 2 * 1024 * 1024;
    unsigned short* xb  = (unsigned short*)d_ws;         // [0,  4MB)
    unsigned short* w1b = xb  + NE;                      // [4,  8MB)
    unsigned short* w3b = w1b + NE;                      // [8, 12MB)
    unsigned short* vb  = w3b + NE;                      // [12,16MB)
    unsigned short* hb  = vb  + NE;                      // [16,24MB)
    unsigned short* h2b = hb  + 2 * NE;                  // [24,32MB)

    // cvt x, W1 (L1's operands)
    cvt2<<<4096, 256, 0, stream>>>(x, W1, xb, w1b);
    // L1: h = relu(x @ W1^T + b1), 64x64, grid 1024, PIPE2 (32KB);
    // prologue converts W3 -> w3b and vals -> vb (consumers launch later)
    gemm_bt<64, 64, 4, 2, 1, 1, 1><<<1024, 256, 0, stream>>>(
        xb, w1b, b1, hb, 2048, 2048, 1024, W3, w3b, vals, vb);
    // BSR + relu, grid 1024 (4/CU)
    bsr_layer<<<1024, 256, 0, stream>>>(hb, crow, cols, vb, b2, h2b);
    // L3: out = h2 @ W3^T + b3, 64x32, grid 1024, PIPE3 (36KB -> still 4/CU)
    gemm_bt<64, 32, 4, 3, 0, 0, 0><<<1024, 256, 0, stream>>>(
        h2b, w3b, b3, out, 2048, 1024, 2048,
        nullptr, nullptr, nullptr, nullptr);

    (void)in_sizes; (void)n_in; (void)out_size; (void)ws_size;
}

// Round 17
// 75.422 us; speedup vs baseline: 1.0111x; 1.0111x over previous
//
#include <hip/hip_runtime.h>
#include <hip/hip_bf16.h>

// ---------------------------------------------------------------------------
// BlockedMLP: out = (relu(bsr(relu(x@W1^T+b1))+b2)) @ W3^T + b3
// B=2048, IN=1024, H=2048, OUT=1024, BS=32, RB=CB=64, 32 blocks/row
// FINAL (R17 = R15-exact, measured best 75.9us):
//   cvt2 (x,W1) -> L1 64x64 PIPE2 grid1024 (+prologue-cvt of W3,vals,
//   hidden under pipeline fill) -> BSR 2-nnz/K-step grid1024 (4/CU) ->
//   L3 64x32 PIPE2 grid1024 (4/CU).
// Session evidence: occupancy >=4 blocks/CU is the binding lever; pipeline
// depth at constant occupancy = null (R16); 8-phase needs 256^2 tiles ->
// grid 64 = 1/4 CU util, excluded (R10/m232); grid.sync ~200us (R14);
// fp8 fails accuracy; split-K/atomics/memset all net-negative (R6-R11).
// ---------------------------------------------------------------------------

typedef __attribute__((ext_vector_type(8))) short bf16x8;
typedef __attribute__((ext_vector_type(4))) float f32x4;

__device__ __forceinline__ unsigned short f2bf(float f) {
    union { float f; unsigned int u; } c; c.f = f;
    unsigned int u = c.u;
    u += 0x7fffu + ((u >> 16) & 1u);   // round-to-nearest-even
    return (unsigned short)(u >> 16);
}

__device__ __forceinline__ void async16(const void* g, void* l) {
    __builtin_amdgcn_global_load_lds(
        (const __attribute__((address_space(1))) void*)g,
        (__attribute__((address_space(3))) void*)l,
        16, 0, 0);
}

template<int N>
__device__ __forceinline__ void vm_wait() {
    asm volatile("s_waitcnt vmcnt(%0)" :: "n"(N) : "memory");
}
__device__ __forceinline__ void barrier() {
    asm volatile("" ::: "memory");
    __builtin_amdgcn_s_barrier();
    asm volatile("" ::: "memory");
}

// ---------------------------------------------------------------------------
// cvt2: f32 -> bf16 for x and W1 only (2 x 2^21 elems), grid 4096
// ---------------------------------------------------------------------------
__global__ __launch_bounds__(256) void cvt2(
    const float* __restrict__ x, const float* __restrict__ w1,
    unsigned short* __restrict__ xb, unsigned short* __restrict__ w1b)
{
    const int NE = 1 << 21;
    int e = (blockIdx.x * 256 + threadIdx.x) * 4;
    int a = e >> 21;
    int off = e & (NE - 1);
    const float* src = a ? w1 : x;
    unsigned short* dst = a ? w1b : xb;
    float4 vv = *reinterpret_cast<const float4*>(src + off);
    ushort4 o;
    o.x = f2bf(vv.x); o.y = f2bf(vv.y); o.z = f2bf(vv.z); o.w = f2bf(vv.w);
    *reinterpret_cast<ushort4*>(dst + off) = o;
}

// ---------------------------------------------------------------------------
// bf16 GEMM, B^T form: BM x BN tile, BK=64, 4 waves (2x2), PIPE-deep LDS
// dbuf, two-barrier counted-vmcnt, XOR swizzle chunk^(row&7), XCD-pinned.
// PRECVT: convert 2048 elems each of two f32 arrays per block (producers
// for LATER kernels; hidden under pipeline fill).
// OUTMODE: 0 = f32+bias, 1 = bf16+bias.
// ---------------------------------------------------------------------------
template<int BM, int BN, int MCL, int PIPE, int RELU, int OUTMODE, int PRECVT>
__global__ __launch_bounds__(256) void gemm_bt(
    const unsigned short* __restrict__ A,
    const unsigned short* __restrict__ B,
    const float* __restrict__ bias,
    void* __restrict__ C0,
    int M, int N, int K,
    const float* __restrict__ cs0, unsigned short* __restrict__ cd0,
    const float* __restrict__ cs1, unsigned short* __restrict__ cd1)
{
    constexpr int BK = 64;
    constexpr int MR = BM / 32;
    constexpr int NR = BN / 32;
    constexpr int AI = BM / 32;
    constexpr int BI = BN / 32;
    constexpr int LPS = AI + BI;
    __shared__ unsigned short As[PIPE][BM * BK];
    __shared__ unsigned short Bs[PIPE][BN * BK];

    const int t = threadIdx.x;
    const int w = t >> 6;
    const int l = t & 63;
    const int id = blockIdx.x;

    const int xcd = id & 7;
    const int j = id >> 3;
    const int mt = xcd * MCL + (j & (MCL - 1));
    const int nt = j / MCL;
    const int bm = mt * BM;
    const int bn = nt * BN;

    const int wm = (w >> 1) * (BM / 2);
    const int wn = (w & 1) * (BN / 2);

    f32x4 acc[MR][NR];
    #pragma unroll
    for (int i = 0; i < MR; ++i)
        #pragma unroll
        for (int jj = 0; jj < NR; ++jj)
            acc[i][jj] = (f32x4){0.f, 0.f, 0.f, 0.f};

    const int arow = bm + w * (BM / 4) + (l >> 3);
    const int brow = bn + w * (BN / 4) + (l >> 3);
    const int scol = ((l & 7) ^ (l >> 3)) * 8;
    const int fr = l & 15;
    const int kg = l >> 4;
    const int fq = l >> 4;

    auto stage = [&](int buf, int kt) {
        const int k0 = kt * BK;
        #pragma unroll
        for (int i = 0; i < AI; ++i)
            async16(A + (size_t)(arow + i * 8) * K + k0 + scol,
                    &As[buf][(w * (BM / 4) + i * 8) * BK]);
        #pragma unroll
        for (int i = 0; i < BI; ++i)
            async16(B + (size_t)(brow + i * 8) * K + k0 + scol,
                    &Bs[buf][(w * (BN / 4) + i * 8) * BK]);
    };

    auto compute = [&](int buf) {
        #pragma unroll
        for (int kk = 0; kk < 2; ++kk) {
            const int pc = ((kk * 4 + kg) ^ (fr & 7)) * 8;
            bf16x8 af[MR], bg[NR];
            #pragma unroll
            for (int i = 0; i < MR; ++i)
                af[i] = *reinterpret_cast<const bf16x8*>(
                    &As[buf][(wm + i * 16 + fr) * BK + pc]);
            #pragma unroll
            for (int jj = 0; jj < NR; ++jj)
                bg[jj] = *reinterpret_cast<const bf16x8*>(
                    &Bs[buf][(wn + jj * 16 + fr) * BK + pc]);
            #pragma unroll
            for (int i = 0; i < MR; ++i)
                #pragma unroll
                for (int jj = 0; jj < NR; ++jj)
                    acc[i][jj] = __builtin_amdgcn_mfma_f32_16x16x32_bf16(
                        af[i], bg[jj], acc[i][jj], 0, 0, 0);
        }
    };

    const int nK = K >> 6;
    stage(0, 0);
    stage(1, 1);
    if (PIPE == 3) stage(2, 2);

    if (PRECVT) {
        // converts run while the first staged tiles are in flight; these
        // f32 loads are NEWER than the staged tiles in the vmcnt queue, so
        // counted waits on older staging loads remain conservative-safe.
        const int off = id * 2048 + t * 8;
        float4 a0 = *reinterpret_cast<const float4*>(cs0 + off);
        float4 a1 = *reinterpret_cast<const float4*>(cs0 + off + 4);
        float4 b0 = *reinterpret_cast<const float4*>(cs1 + off);
        float4 b1 = *reinterpret_cast<const float4*>(cs1 + off + 4);
        ushort4 o0, o1, o2, o3;
        o0.x = f2bf(a0.x); o0.y = f2bf(a0.y); o0.z = f2bf(a0.z); o0.w = f2bf(a0.w);
        o1.x = f2bf(a1.x); o1.y = f2bf(a1.y); o1.z = f2bf(a1.z); o1.w = f2bf(a1.w);
        o2.x = f2bf(b0.x); o2.y = f2bf(b0.y); o2.z = f2bf(b0.z); o2.w = f2bf(b0.w);
        o3.x = f2bf(b1.x); o3.y = f2bf(b1.y); o3.z = f2bf(b1.z); o3.w = f2bf(b1.w);
        *reinterpret_cast<ushort4*>(cd0 + off)     = o0;
        *reinterpret_cast<ushort4*>(cd0 + off + 4) = o1;
        *reinterpret_cast<ushort4*>(cd1 + off)     = o2;
        *reinterpret_cast<ushort4*>(cd1 + off + 4) = o3;
    }

    int cur = 0;
    for (int kt = 0; kt < nK; ++kt) {
        if (PIPE == 3) {
            if (kt < nK - 2)       vm_wait<2 * LPS>();
            else if (kt == nK - 2) vm_wait<LPS>();
            else                   vm_wait<0>();
        } else {
            if (kt < nK - 1)       vm_wait<LPS>();
            else                   vm_wait<0>();
        }
        barrier();
        compute(cur);
        if (kt + PIPE < nK) {
            barrier();
            stage(cur, kt + PIPE);
        } else if (kt + 1 < nK) {
            barrier();
        }
        cur = (cur == PIPE - 1) ? 0 : cur + 1;
    }

    // epilogue: C/D layout col = l&15, row = (l>>4)*4 + v
    #pragma unroll
    for (int i = 0; i < MR; ++i) {
        const int row0 = bm + wm + i * 16 + fq * 4;
        #pragma unroll
        for (int jj = 0; jj < NR; ++jj) {
            const int col = bn + wn + jj * 16 + fr;
            const float bv = bias[col];
            #pragma unroll
            for (int v = 0; v < 4; ++v) {
                float r = acc[i][jj][v] + bv;
                if (RELU) r = fmaxf(r, 0.f);
                const size_t off = (size_t)(row0 + v) * N + col;
                if (OUTMODE == 1) ((unsigned short*)C0)[off] = f2bf(r);
                else              ((float*)C0)[off] = r;
            }
        }
    }
}

// ---------------------------------------------------------------------------
// BSR layer (R8-exact): 2 nnz blocks per K-step (K-concat), counted-vmcnt,
// grid 1024 (4 blocks/CU), XCD-pinned, 128B LDS rows XOR-swizzled.
// ---------------------------------------------------------------------------
__global__ __launch_bounds__(256) void bsr_layer(
    const unsigned short* __restrict__ h,     // 2048 x 2048 bf16
    const int* __restrict__ crow,
    const int* __restrict__ cols,
    const unsigned short* __restrict__ vals,  // nnz x 32 x 32 bf16
    const float* __restrict__ b2,
    unsigned short* __restrict__ h2)          // 2048 x 2048 bf16
{
    __shared__ unsigned short Hs[2][128 * 64];
    __shared__ unsigned short Vs[2][32 * 64];
    __shared__ int colsS[64];
    const int t = threadIdx.x;
    const int w = t >> 6;
    const int l = t & 63;

    const int id = blockIdx.x;
    const int xcd = id & 7;
    const int j2 = id >> 3;
    const int bt = xcd * 2 + (j2 & 1);
    const int r  = j2 >> 1;
    const int bm = bt * 128;

    const int s = crow[r];
    const int cnt = crow[r + 1] - s;
    const int wrow = w * 32;

    if (t < cnt) colsS[t] = cols[s + t];

    f32x4 acc[2][2];
    #pragma unroll
    for (int i = 0; i < 2; ++i)
        #pragma unroll
        for (int jj = 0; jj < 2; ++jj)
            acc[i][jj] = (f32x4){0.f, 0.f, 0.f, 0.f};

    const int fr = l & 15;
    const int kg = l >> 4;
    const int lr = l >> 3;
    const int sc = (l & 7) ^ lr;

    auto stage = [&](int buf, int js) {
        const int n0 = s + 2 * js;
        const bool tail = (2 * js + 1 >= cnt);
        const int c0 = colsS[2 * js];
        const int c1 = tail ? c0 : colsS[2 * js + 1];
        const int n1 = tail ? n0 : n0 + 1;
        #pragma unroll
        for (int i = 0; i < 4; ++i) {
            const int row = bm + w * 32 + i * 8 + lr;
            const int col = (sc & 4) ? c1 * 32 + (sc & 3) * 8 : c0 * 32 + sc * 8;
            async16(h + (size_t)row * 2048 + col,
                    &Hs[buf][(w * 32 + i * 8) * 64]);
        }
        const int vrow = w * 8 + lr;
        if (!tail || !(sc & 4)) {
            const unsigned short* src =
                vals + (size_t)((sc & 4) ? n1 : n0) * 1024 + vrow * 32 + (sc & 3) * 8;
            async16(src, &Vs[buf][(w * 8) * 64]);
        } else {
            bf16x8 z = (bf16x8){0,0,0,0,0,0,0,0};
            *reinterpret_cast<bf16x8*>(&Vs[buf][vrow * 64 + (l & 7) * 8]) = z;
        }
    };

    auto compute = [&](int buf) {
        #pragma unroll
        for (int kk = 0; kk < 2; ++kk) {
            const int pc = ((kk * 4 + kg) ^ (fr & 7)) * 8;
            bf16x8 af[2], bg[2];
            #pragma unroll
            for (int i = 0; i < 2; ++i)
                af[i] = *reinterpret_cast<const bf16x8*>(
                    &Hs[buf][(wrow + i * 16 + fr) * 64 + pc]);
            #pragma unroll
            for (int jj = 0; jj < 2; ++jj)
                bg[jj] = *reinterpret_cast<const bf16x8*>(
                    &Vs[buf][(jj * 16 + fr) * 64 + pc]);
            #pragma unroll
            for (int i = 0; i < 2; ++i)
                #pragma unroll
                for (int jj = 0; jj < 2; ++jj)
                    acc[i][jj] = __builtin_amdgcn_mfma_f32_16x16x32_bf16(
                        af[i], bg[jj], acc[i][jj], 0, 0, 0);
        }
    };

    __syncthreads();
    const int nsteps = (cnt + 1) >> 1;
    stage(0, 0);
    if (nsteps > 1) stage(1, 1);
    int cur = 0;
    for (int js = 0; js < nsteps - 1; ++js) {
        vm_wait<5>();
        barrier();
        compute(cur);
        barrier();
        if (js + 2 < nsteps) stage(cur, js + 2);
        cur ^= 1;
    }
    vm_wait<0>();
    barrier();
    compute(cur);

    const int fq = l >> 4;
    #pragma unroll
    for (int i = 0; i < 2; ++i) {
        const int row0 = bm + wrow + i * 16 + fq * 4;
        #pragma unroll
        for (int jj = 0; jj < 2; ++jj) {
            const int col = r * 32 + jj * 16 + fr;
            const float bv = b2[col];
            #pragma unroll
            for (int v = 0; v < 4; ++v) {
                float rv = fmaxf(acc[i][jj][v] + bv, 0.f);
                h2[(size_t)(row0 + v) * 2048 + col] = f2bf(rv);
            }
        }
    }
}

// ---------------------------------------------------------------------------
extern "C" void kernel_launch(void* const* d_in, const int* in_sizes, int n_in,
                              void* d_out, int out_size, void* d_ws, size_t ws_size,
                              hipStream_t stream) {
    const float* x    = (const float*)d_in[0];   // 2048x1024
    const float* W1   = (const float*)d_in[1];   // 2048x1024
    const float* b1   = (const float*)d_in[2];   // 2048
    const int*   crow = (const int*)d_in[3];     // 65
    const int*   cols = (const int*)d_in[4];     // 2048
    const float* vals = (const float*)d_in[5];   // 2048x32x32
    const float* b2   = (const float*)d_in[6];   // 2048
    const float* W3   = (const float*)d_in[7];   // 1024x2048
    const float* b3   = (const float*)d_in[8];   // 1024
    float* out = (float*)d_out;                  // 2048x1024 f32

    const int NE = 2 * 1024 * 1024;
    unsigned short* xb  = (unsigned short*)d_ws;         // [0,  4MB)
    unsigned short* w1b = xb  + NE;                      // [4,  8MB)
    unsigned short* w3b = w1b + NE;                      // [8, 12MB)
    unsigned short* vb  = w3b + NE;                      // [12,16MB)
    unsigned short* hb  = vb  + NE;                      // [16,24MB)
    unsigned short* h2b = hb  + 2 * NE;                  // [24,32MB)

    // cvt x, W1 (L1's operands)
    cvt2<<<4096, 256, 0, stream>>>(x, W1, xb, w1b);
    // L1: h = relu(x @ W1^T + b1), 64x64, grid 1024, PIPE2 (32KB);
    // prologue converts W3 -> w3b and vals -> vb (consumers launch later)
    gemm_bt<64, 64, 4, 2, 1, 1, 1><<<1024, 256, 0, stream>>>(
        xb, w1b, b1, hb, 2048, 2048, 1024, W3, w3b, vals, vb);
    // BSR + relu, grid 1024 (4/CU)
    bsr_layer<<<1024, 256, 0, stream>>>(hb, crow, cols, vb, b2, h2b);
    // L3: out = h2 @ W3^T + b3, 64x32, grid 1024, PIPE2 (24KB)
    gemm_bt<64, 32, 4, 2, 0, 0, 0><<<1024, 256, 0, stream>>>(
        h2b, w3b, b3, out, 2048, 1024, 2048,
        nullptr, nullptr, nullptr, nullptr);

    (void)in_sizes; (void)n_in; (void)out_size; (void)ws_size;
}